// Round 1
// baseline (546.101 us; speedup 1.0000x reference)
//
#include <hip/hip_runtime.h>

#define NRAYS 131072
#define NS 64      // coarse samples (z_vals per ray)
#define NI 128     // importance samples
#define NM 63      // bins (z_mid entries) == cdf length
#define NW 62      // interior weights used
#define NT 192     // merged samples per ray (NS + NI)

__global__ __launch_bounds__(256) void importance_kernel(
    const float* __restrict__ rays_o,
    const float* __restrict__ rays_d,
    const float* __restrict__ z_vals,
    const float* __restrict__ weights,
    float* __restrict__ out_pts,    // [N, 192, 3]
    float* __restrict__ out_zall,   // [N, 192]
    float* __restrict__ out_zs)     // [N, 128]
{
    __shared__ float s_zv[4][NS];     // z_vals
    __shared__ float s_zm[4][NS];     // z_mid (63 used)
    __shared__ float s_cdf[4][NS];    // cdf (63 used)
    __shared__ float s_zs[4][NI];     // importance samples (sorted)
    __shared__ float s_zall[4][NT];   // merged
    __shared__ float s_od[4][6];      // o.xyz, d.xyz

    const int wave = threadIdx.x >> 6;
    const int lane = threadIdx.x & 63;
    const int ray  = blockIdx.x * 4 + wave;
    if (ray >= NRAYS) return;

    const float* zv_g = z_vals  + (size_t)ray * NS;
    const float* w_g  = weights + (size_t)ray * NS;

    // ---- stage inputs ----
    const float zvl = zv_g[lane];
    s_zv[wave][lane] = zvl;
    if (lane < 6)
        s_od[wave][lane] = (lane < 3) ? rays_o[ray * 3 + lane]
                                      : rays_d[ray * 3 + lane - 3];
    // interior weights: weights[ray][1..62]
    float wl = (lane < NW) ? (w_g[lane + 1] + 1e-5f) : 0.0f;
    __syncthreads();

    // ---- z_mid ----
    if (lane < NM)
        s_zm[wave][lane] = 0.5f * (s_zv[wave][lane] + s_zv[wave][lane + 1]);

    // ---- inclusive scan of wl (Hillis-Steele over 64 lanes) ----
    float scan = wl;
    #pragma unroll
    for (int off = 1; off < 64; off <<= 1) {
        float up = __shfl_up(scan, off, 64);
        if (lane >= off) scan += up;
    }
    const float total = __shfl(scan, NW - 1, 64);  // lane 61 holds full sum
    // cdf[0] = 0 ; cdf[l+1] = scan_l / total
    if (lane == 0) s_cdf[wave][0] = 0.0f;
    if (lane < NW) s_cdf[wave][lane + 1] = scan / total;
    __syncthreads();

    // ---- inverse-CDF sampling: 2 samples per lane ----
    const float* cdfp = s_cdf[wave];
    const float* zmp  = s_zm[wave];
    #pragma unroll
    for (int rep = 0; rep < 2; rep++) {
        const int j = lane + rep * 64;
        // np.linspace(0,1,128): round_f32(j/127 computed in f64)
        const float u = (float)((double)j * (1.0 / 127.0));
        // searchsorted(cdf, u, side='right') over cdf[0..62]
        int lo = 0, hi = NM;
        while (lo < hi) {
            const int mid = (lo + hi) >> 1;
            if (cdfp[mid] <= u) lo = mid + 1; else hi = mid;
        }
        int below = lo - 1; if (below < 0) below = 0;
        int above = lo;     if (above > NM - 1) above = NM - 1;
        const float cb = cdfp[below], ca = cdfp[above];
        const float bb = zmp[below],  ba = zmp[above];
        float denom = ca - cb;
        if (denom < 1e-5f) denom = 1.0f;
        const float t = (u - cb) / denom;
        s_zs[wave][j] = bb + t * (ba - bb);
    }
    __syncthreads();

    // ---- merge sorted z_vals (64) + z_samples (128) by rank ----
    const float* zsp = s_zs[wave];
    const float* zvp = s_zv[wave];
    {
        // z_vals element: pos = lane + count(zs < a)   (A wins ties)
        const float a = zvl;
        int lo = 0, hi = NI;
        while (lo < hi) {
            const int mid = (lo + hi) >> 1;
            if (zsp[mid] < a) lo = mid + 1; else hi = mid;
        }
        s_zall[wave][lane + lo] = a;
    }
    #pragma unroll
    for (int rep = 0; rep < 2; rep++) {
        // z_samples element: pos = j + count(zv <= b)
        const int j = lane + rep * 64;
        const float b = zsp[j];
        int lo = 0, hi = NS;
        while (lo < hi) {
            const int mid = (lo + hi) >> 1;
            if (zvp[mid] <= b) lo = mid + 1; else hi = mid;
        }
        s_zall[wave][j + lo] = b;
    }
    __syncthreads();

    // ---- outputs (all lane-contiguous coalesced dword stores) ----
    const float o0 = s_od[wave][0], o1 = s_od[wave][1], o2 = s_od[wave][2];
    const float d0 = s_od[wave][3], d1 = s_od[wave][4], d2 = s_od[wave][5];
    const float* zallp = s_zall[wave];

    const size_t pts_base = (size_t)ray * (NT * 3);
    #pragma unroll
    for (int rep = 0; rep < 9; rep++) {
        const int i = lane + rep * 64;
        const int k = i / 3;            // magic-mul div
        const int d = i - 3 * k;
        const float z = zallp[k];
        const float o  = (d == 0) ? o0 : ((d == 1) ? o1 : o2);
        const float dd = (d == 0) ? d0 : ((d == 1) ? d1 : d2);
        out_pts[pts_base + i] = o + dd * z;
    }
    const size_t za_base = (size_t)ray * NT;
    #pragma unroll
    for (int rep = 0; rep < 3; rep++) {
        const int i = lane + rep * 64;
        out_zall[za_base + i] = zallp[i];
    }
    const size_t zs_base = (size_t)ray * NI;
    #pragma unroll
    for (int rep = 0; rep < 2; rep++) {
        const int i = lane + rep * 64;
        out_zs[zs_base + i] = zsp[i];
    }
}

extern "C" void kernel_launch(void* const* d_in, const int* in_sizes, int n_in,
                              void* d_out, int out_size, void* d_ws, size_t ws_size,
                              hipStream_t stream) {
    const float* rays_o  = (const float*)d_in[0];
    const float* rays_d  = (const float*)d_in[1];
    const float* z_vals  = (const float*)d_in[2];
    const float* weights = (const float*)d_in[3];

    float* out      = (float*)d_out;
    float* out_pts  = out;                                  // N*192*3
    float* out_zall = out + (size_t)NRAYS * NT * 3;         // N*192
    float* out_zs   = out_zall + (size_t)NRAYS * NT;        // N*128

    dim3 grid(NRAYS / 4), block(256);
    hipLaunchKernelGGL(importance_kernel, grid, block, 0, stream,
                       rays_o, rays_d, z_vals, weights,
                       out_pts, out_zall, out_zs);
}